// Round 13
// baseline (940.446 us; speedup 1.0000x reference)
//
#include <hip/hip_runtime.h>
#include <hip/hip_bf16.h>

// Problem constants (reference: T,H,I,E,K = 4096,1024,2048,32,4)
#define T_TOK 4096
#define H_DIM 1024
#define I_DIM 2048
#define N_EXP 32
#define TOPK  4
#define TKTOT (T_TOK * TOPK)      // 16384 expert-row slots
#define ROWS_MAX 24576            // 4096 shared rows + <=20480 padded expert rows
#define MAX_TILES 192             // 32 shared tiles + <=159 expert tiles
#define BM 128
#define BK 64
#define LDB 72                    // BK + 8 f16 pad -> 144 B rows (16B-aligned)

typedef _Float16 f16;
typedef __attribute__((ext_vector_type(2))) f16  f16x2;
typedef __attribute__((ext_vector_type(4))) f16  f16x4;
typedef __attribute__((ext_vector_type(8))) f16  f16x8;
typedef __attribute__((ext_vector_type(4))) float f32x4;

__device__ __forceinline__ void sfence() { __builtin_amdgcn_sched_barrier(0); }
// single per-k-step barrier: this wave's LDS writes done; global loads (A
// frags, next B fetch) stay in flight across it (lgkm only, NO vmcnt).
__device__ __forceinline__ void bar_pre() {
  sfence();
  asm volatile("s_waitcnt lgkmcnt(0)" ::: "memory");
  sfence();
  __builtin_amdgcn_s_barrier();
  sfence();
}

// ---------------------------------------------------------------- prep ----
__global__ void prep_kernel(const float* __restrict__ x, f16* __restrict__ xb,
                            int* __restrict__ row_token,
                            int* __restrict__ counts) {
  int gid = blockIdx.x * blockDim.x + threadIdx.x;   // 0 .. T*H/4-1
  float4 v = *(const float4*)(x + (size_t)gid * 4);
  f16x4 hv = { (f16)v.x, (f16)v.y, (f16)v.z, (f16)v.w };
  *(f16x4*)(xb + (size_t)gid * 4) = hv;
  if (gid < ROWS_MAX) row_token[gid] = (gid < T_TOK) ? gid : 0;
  if (gid < N_EXP) counts[gid] = 0;
}

// -------------------------------------------------------------- router ----
__global__ void router_kernel(const float* __restrict__ x,
                              const float* __restrict__ rw,
                              int* __restrict__ expert_sel,
                              float* __restrict__ weight_sel,
                              int* __restrict__ counts) {
  int wid = threadIdx.x >> 6, lane = threadIdx.x & 63;
  int t = blockIdx.x * 4 + wid;
  float xr[16];
#pragma unroll
  for (int j = 0; j < 16; ++j) xr[j] = x[(size_t)t * H_DIM + lane + j * 64];
  float l[32];
#pragma unroll
  for (int e = 0; e < 32; ++e) {
    float p = 0.f;
#pragma unroll
    for (int j = 0; j < 16; ++j) p += xr[j] * rw[(size_t)e * H_DIM + lane + j * 64];
#pragma unroll
    for (int off = 32; off; off >>= 1) p += __shfl_xor(p, off, 64);
    l[e] = p;
  }
  if (lane == 0) {
    unsigned used = 0;
    int sel[4]; float lv[4];
#pragma unroll
    for (int k = 0; k < 4; ++k) {
      float bv = -3.4e38f; int bi = 0;
#pragma unroll
      for (int e = 0; e < 32; ++e) {
        bool better = (((used >> e) & 1u) == 0u) && (l[e] > bv);
        bv = better ? l[e] : bv;
        bi = better ? e : bi;
      }
      used |= 1u << bi; sel[k] = bi; lv[k] = bv;
    }
    float m = lv[0];
    float p0 = __expf(lv[0] - m), p1 = __expf(lv[1] - m);
    float p2 = __expf(lv[2] - m), p3 = __expf(lv[3] - m);
    float s = p0 + p1 + p2 + p3;
    float wv[4] = { p0 / s, p1 / s, p2 / s, p3 / s };
#pragma unroll
    for (int k = 0; k < 4; ++k) {
      expert_sel[t * 4 + k] = sel[k];
      weight_sel[t * 4 + k] = wv[k];
      atomicAdd(&counts[sel[k]], 1);
    }
  }
}

// ---------------------------------------------------------------- scan ----
// wave-parallel: lane e handles expert e; prefix-sums via shfl_up.
__global__ void scan_kernel(const int* __restrict__ counts, int* __restrict__ cursor,
                            int* __restrict__ tile_expert, int* __restrict__ tile_row0,
                            int* __restrict__ ntiles) {
  int lane = threadIdx.x;                      // 64 threads, one wave
  if (lane < T_TOK / BM) { tile_expert[lane] = N_EXP; tile_row0[lane] = lane * BM; }
  int nte = 0, rows = 0;
  if (lane < N_EXP) {
    int c = counts[lane];
    nte = (c + BM - 1) / BM;
    rows = nte * BM;
  }
  int pnte = nte, prows = rows;
#pragma unroll
  for (int off = 1; off < 64; off <<= 1) {
    int t1 = __shfl_up(pnte, off, 64);
    int t2 = __shfl_up(prows, off, 64);
    if (lane >= off) { pnte += t1; prows += t2; }
  }
  int excl_nte = pnte - nte, excl_rows = prows - rows;
  if (lane < N_EXP) {
    int pos = T_TOK + excl_rows;
    cursor[lane] = pos;
    int tb = T_TOK / BM + excl_nte;
    for (int i = 0; i < nte; ++i) {
      tile_expert[tb + i] = lane;
      tile_row0[tb + i] = pos + i * BM;
    }
    if (lane == N_EXP - 1) ntiles[0] = tb + nte;
  }
}

// ------------------------------------------------------------- scatter ----
__global__ void scatter_kernel(const int* __restrict__ expert_sel,
                               int* __restrict__ cursor,
                               int* __restrict__ row_token,
                               int* __restrict__ slot_of) {
  int i = blockIdx.x * blockDim.x + threadIdx.x;
  if (i >= TKTOT) return;
  int e = expert_sel[i];
  int pos = atomicAdd(&cursor[e], 1);
  row_token[pos] = i >> 2;
  slot_of[i] = pos;
}

// ------------------------- B staging helpers (fetch regs / cvt+write LDS) --
// gemm1 (BN=64): thread covers 2 n x 8 k via float2 rows (8 VMEM loads).
struct Bf2 { float2 g[8]; };
__device__ __forceinline__ Bf2 fetch_b2(const float* __restrict__ src, size_t ldn) {
  Bf2 r;
#pragma unroll
  for (int j = 0; j < 8; ++j) r.g[j] = *(const float2*)(src + (size_t)j * ldn);
  return r;
}
__device__ __forceinline__ void write_b2(const Bf2& b, f16* __restrict__ Bs,
                                         int nq, int kr) {
  const float* ga = (const float*)b.g;        // ga[j*2 + comp]
  int ks = (8 * kr) ^ ((nq & 7) << 3);        // swizzled 16B slot (f16 units)
#pragma unroll
  for (int i = 0; i < 2; ++i) {
    union { f16x2 p[4]; f16x8 v; } u;
#pragma unroll
    for (int j = 0; j < 4; ++j)
      u.p[j] = __builtin_bit_cast(
          f16x2, __builtin_amdgcn_cvt_pkrtz(ga[(2 * j) * 2 + i],
                                            ga[(2 * j + 1) * 2 + i]));
    *(f16x8*)(Bs + (2 * nq + i) * LDB + ks) = u.v;
  }
}
__device__ __forceinline__ int rswz1(int row, int kf16) {
  return kf16 ^ (((row >> 1) & 7) << 3);
}

// gemm2 (BN=128): thread covers 4 n x 8 k via float4 rows (8 VMEM loads).
struct Bf4 { float4 g[8]; };
__device__ __forceinline__ Bf4 fetch_b4(const float* __restrict__ src, size_t ldn) {
  Bf4 r;
#pragma unroll
  for (int j = 0; j < 8; ++j) r.g[j] = *(const float4*)(src + (size_t)j * ldn);
  return r;
}
__device__ __forceinline__ void write_b4(const Bf4& b, f16* __restrict__ Bs,
                                         int nq, int kr) {
  const float* ga = (const float*)b.g;        // ga[j*4 + comp]
  int ks = (8 * kr) ^ ((nq & 7) << 3);
#pragma unroll
  for (int i = 0; i < 4; ++i) {
    union { f16x2 p[4]; f16x8 v; } u;
#pragma unroll
    for (int j = 0; j < 4; ++j)
      u.p[j] = __builtin_bit_cast(
          f16x2, __builtin_amdgcn_cvt_pkrtz(ga[(2 * j) * 4 + i],
                                            ga[(2 * j + 1) * 4 + i]));
    *(f16x8*)(Bs + (4 * nq + i) * LDB + ks) = u.v;
  }
}
__device__ __forceinline__ int rswz2(int row, int kf16) {
  return kf16 ^ (((row >> 2) & 7) << 3);
}

// ---------------------------------------------------------------- GEMM1 ---
// 128x64 tile of gate AND up. A fragments read DIRECTLY from global (xb is
// L2/L3-resident; loads issued pre-barrier, fly across it). B LDS double-
// buffered -> ONE barrier per k-step, race-free (a wave cannot reach
// write(k+2) without passing barrier(k+1)).
__global__ __launch_bounds__(256, 3) void gemm1_kernel(
    const f16* __restrict__ xb,
    const float* __restrict__ gate_w, const float* __restrict__ up_w,
    const float* __restrict__ sgw, const float* __restrict__ suw,
    const int* __restrict__ row_token,
    const int* __restrict__ tile_expert, const int* __restrict__ tile_row0,
    const int* __restrict__ ntiles, f16* __restrict__ hbuf) {
  // XCD-aware swizzle: grid 192*32 = 6144 = 8*768 consecutive per XCD
  int d = blockIdx.y * gridDim.x + blockIdx.x;
  int l = (d & 7) * 768 + (d >> 3);
  int bx = l % MAX_TILES;
  int n0 = (l / MAX_TILES) * 64;
  if (bx >= ntiles[0]) return;
  int e = tile_expert[bx];
  int row0 = tile_row0[bx];
  const float* wg = (e < N_EXP) ? gate_w + (size_t)e * H_DIM * I_DIM : sgw;
  const float* wu = (e < N_EXP) ? up_w   + (size_t)e * H_DIM * I_DIM : suw;

  // LDS: B only, dbuf x (gate,up): 2*2*64*72 = 18432 f16 = 36.9 KB
  __shared__ __align__(16) f16 smem[2 * 2 * 64 * LDB];
  f16 (*Ct)[LDB] = (f16(*)[LDB])smem;   // epilogue reuse (9216 f16 = buf0)

  int tid = threadIdx.x;
  int lane = tid & 63, wid = tid >> 6;
  int wm = wid >> 1, wn = wid & 1;
  int lr = lane & 15, lk = (lane >> 4) * 8;
  int nq = tid & 31, kr = tid >> 5;

  // per-thread A row bases (4 m-frags, row = row0 + wm*64 + m*16 + lr)
  const f16* abase[4];
#pragma unroll
  for (int m = 0; m < 4; ++m) {
    int atok = row_token[row0 + wm * 64 + m * 16 + lr];
    abase[m] = xb + (size_t)atok * H_DIM + lk;
  }
  const float* wgp = wg + (size_t)(8 * kr) * I_DIM + n0 + 2 * nq;
  const float* wup = wu + (size_t)(8 * kr) * I_DIM + n0 + 2 * nq;

  f32x4 accg[4][2], accu[4][2];
#pragma unroll
  for (int m = 0; m < 4; ++m)
#pragma unroll
    for (int n = 0; n < 2; ++n) { accg[m][n] = (f32x4)0.f; accu[m][n] = (f32x4)0.f; }

  const int NK = H_DIM / BK;                 // 16
  // prologue: B(0) to regs
  Bf2 pg = fetch_b2(wgp, I_DIM);
  Bf2 pu = fetch_b2(wup, I_DIM);
  sfence();

  for (int ks = 0; ks < NK; ++ks) {
    f16* Bgw = smem + (ks & 1) * 9216;       // this step's buffer
    f16* Buw = Bgw + 4608;
    write_b2(pg, Bgw, nq, kr);               // reg-wait drains B(ks) arrival
    write_b2(pu, Buw, nq, kr);
    if (ks + 1 < NK) {
      pg = fetch_b2(wgp + (size_t)(ks + 1) * BK * I_DIM, I_DIM);
      pu = fetch_b2(wup + (size_t)(ks + 1) * BK * I_DIM, I_DIM);
    }
    // early A frags (kk=0): global loads cross the lgkm-only barrier
    int k0 = ks * BK;
    f16x8 a0[4];
#pragma unroll
    for (int m = 0; m < 4; ++m) a0[m] = *(const f16x8*)(abase[m] + k0);
    bar_pre();                                // ONE barrier per k-step
    __builtin_amdgcn_s_setprio(1);
    { // kk = 0
      f16x8 bg[2], bu[2];
#pragma unroll
      for (int n = 0; n < 2; ++n) {
        int rowb = wn * 32 + n * 16 + lr;
        int ko = rswz1(rowb, lk);
        bg[n] = *(const f16x8*)(Bgw + rowb * LDB + ko);
        bu[n] = *(const f16x8*)(Buw + rowb * LDB + ko);
      }
#pragma unroll
      for (int m = 0; m < 4; ++m)
#pragma unroll
        for (int n = 0; n < 2; ++n) {
          accg[m][n] = __builtin_amdgcn_mfma_f32_16x16x32_f16(a0[m], bg[n], accg[m][n], 0, 0, 0);
          accu[m][n] = __builtin_amdgcn_mfma_f32_16x16x32_f16(a0[m], bu[n], accu[m][n], 0, 0, 0);
        }
    }
    { // kk = 32
      f16x8 a1[4], bg[2], bu[2];
#pragma unroll
      for (int m = 0; m < 4; ++m) a1[m] = *(const f16x8*)(abase[m] + k0 + 32);
#pragma unroll
      for (int n = 0; n < 2; ++n) {
        int rowb = wn * 32 + n * 16 + lr;
        int ko = rswz1(rowb, 32 + lk);
        bg[n] = *(const f16x8*)(Bgw + rowb * LDB + ko);
        bu[n] = *(const f16x8*)(Buw + rowb * LDB + ko);
      }
#pragma unroll
      for (int m = 0; m < 4; ++m)
#pragma unroll
        for (int n = 0; n < 2; ++n) {
          accg[m][n] = __builtin_amdgcn_mfma_f32_16x16x32_f16(a1[m], bg[n], accg[m][n], 0, 0, 0);
          accu[m][n] = __builtin_amdgcn_mfma_f32_16x16x32_f16(a1[m], bu[n], accu[m][n], 0, 0, 0);
        }
    }
    __builtin_amdgcn_s_setprio(0);
    // no post barrier: next step writes the OTHER buffer
  }

  // epilogue: SwiGLU -> LDS bounce -> coalesced f16x8 stores (hbuf LINEAR)
  __syncthreads();                           // all waves done with B LDS
#pragma unroll
  for (int m = 0; m < 4; ++m)
#pragma unroll
    for (int n = 0; n < 2; ++n)
#pragma unroll
      for (int j = 0; j < 4; ++j) {
        float g = accg[m][n][j], u = accu[m][n][j];
        float hv = g / (1.f + __expf(-g)) * u;
        Ct[wm * 64 + m * 16 + (lane >> 4) * 4 + j][wn * 32 + n * 16 + lr] = (f16)hv;
      }
  __syncthreads();
#pragma unroll
  for (int it = 0; it < 4; ++it) {
    int idx = tid + it * 256;
    int r = idx >> 3, g8 = (idx & 7) * 8;
    *(f16x8*)(hbuf + (size_t)(row0 + r) * I_DIM + n0 + g8) = *(const f16x8*)&Ct[r][g8];
  }
}

// ---------------------------------------------------------------- GEMM2 ---
// 128x128 tile of down. A fragments directly from hbuf (L3-resident);
// B LDS dbuf, one barrier per k-step. Output: ybuf f16 (no atomics).
__global__ __launch_bounds__(256, 3) void gemm2_kernel(
    const f16* __restrict__ hbuf,
    const float* __restrict__ down_w, const float* __restrict__ sdw,
    const int* __restrict__ tile_expert, const int* __restrict__ tile_row0,
    const int* __restrict__ ntiles, f16* __restrict__ ybuf) {
  // grid 192*8 = 1536 = 8*192 consecutive per XCD
  int d = blockIdx.y * gridDim.x + blockIdx.x;
  int l = (d & 7) * 192 + (d >> 3);
  int bx = l % MAX_TILES;
  int n0 = (l / MAX_TILES) * 128;
  if (bx >= ntiles[0]) return;
  int e = tile_expert[bx];
  int row0 = tile_row0[bx];
  const float* wd = (e < N_EXP) ? down_w + (size_t)e * I_DIM * H_DIM : sdw;

  // LDS: B dbuf only: 2*128*72 = 18432 f16 = 36.9 KB
  __shared__ __align__(16) f16 smem[2 * 128 * LDB];
  f16 (*Ct)[136] = (f16(*)[136])smem;        // 17408 f16 <= 18432

  int tid = threadIdx.x;
  int lane = tid & 63, wid = tid >> 6;
  int wm = wid >> 1, wn = wid & 1;
  int lr = lane & 15, lk = (lane >> 4) * 8;
  int nq = tid & 31, kr = tid >> 5;

  const f16* abase[4];
#pragma unroll
  for (int m = 0; m < 4; ++m)
    abase[m] = hbuf + (size_t)(row0 + wm * 64 + m * 16 + lr) * I_DIM + lk;
  const float* wdp = wd + (size_t)(8 * kr) * H_DIM + n0 + 4 * nq;

  f32x4 acc[4][4];
#pragma unroll
  for (int m = 0; m < 4; ++m)
#pragma unroll
    for (int n = 0; n < 4; ++n) acc[m][n] = (f32x4)0.f;

  const int NK = I_DIM / BK;                 // 32
  Bf4 pd = fetch_b4(wdp, H_DIM);
  sfence();

  for (int ks = 0; ks < NK; ++ks) {
    f16* Bdw = smem + (ks & 1) * 9216;
    write_b4(pd, Bdw, nq, kr);
    if (ks + 1 < NK)
      pd = fetch_b4(wdp + (size_t)(ks + 1) * BK * H_DIM, H_DIM);
    int k0 = ks * BK;
    f16x8 a0[4];
#pragma unroll
    for (int m = 0; m < 4; ++m) a0[m] = *(const f16x8*)(abase[m] + k0);
    bar_pre();
    __builtin_amdgcn_s_setprio(1);
    { // kk = 0
      f16x8 bd[4];
#pragma unroll
      for (int n = 0; n < 4; ++n) {
        int rowb = wn * 64 + n * 16 + lr;
        bd[n] = *(const f16x8*)(Bdw + rowb * LDB + rswz2(rowb, lk));
      }
#pragma unroll
      for (int m = 0; m < 4; ++m)
#pragma unroll
        for (int n = 0; n < 4; ++n)
          acc[m][n] = __builtin_amdgcn_mfma_f32_16x16x32_f16(a0[m], bd[n], acc[m][n], 0, 0, 0);
    }
    { // kk = 32
      f16x8 a1[4], bd[4];
#pragma unroll
      for (int m = 0; m < 4; ++m) a1[m] = *(const f16x8*)(abase[m] + k0 + 32);
#pragma unroll
      for (int n = 0; n < 4; ++n) {
        int rowb = wn * 64 + n * 16 + lr;
        bd[n] = *(const f16x8*)(Bdw + rowb * LDB + rswz2(rowb, 32 + lk));
      }
#pragma unroll
      for (int m = 0; m < 4; ++m)
#pragma unroll
        for (int n = 0; n < 4; ++n)
          acc[m][n] = __builtin_amdgcn_mfma_f32_16x16x32_f16(a1[m], bd[n], acc[m][n], 0, 0, 0);
    }
    __builtin_amdgcn_s_setprio(0);
  }

  __syncthreads();
#pragma unroll
  for (int m = 0; m < 4; ++m)
#pragma unroll
    for (int n = 0; n < 4; ++n)
#pragma unroll
      for (int j = 0; j < 4; ++j)
        Ct[wm * 64 + m * 16 + (lane >> 4) * 4 + j][wn * 64 + n * 16 + lr] =
            (f16)acc[m][n][j];
  __syncthreads();
#pragma unroll
  for (int it = 0; it < 8; ++it) {
    int idx = tid + it * 256;
    int r = idx >> 4, g8 = (idx & 15) * 8;
    *(f16x8*)(ybuf + (size_t)(row0 + r) * H_DIM + n0 + g8) = *(const f16x8*)&Ct[r][g8];
  }
}

// --------------------------------------------------------------- gather ---
// out[t] = ybuf[t] (shared) + sum_k w[t,k] * ybuf[slot_of[t,k]]
__global__ void gather_kernel(const f16* __restrict__ ybuf,
                              const int* __restrict__ slot_of,
                              const float* __restrict__ weight_sel,
                              float* __restrict__ out) {
  int gid = blockIdx.x * blockDim.x + threadIdx.x;   // T*128
  int t = gid >> 7, s8 = (gid & 127) * 8;
  f16x8 ysh = *(const f16x8*)(ybuf + (size_t)t * H_DIM + s8);
  float a[8];
#pragma unroll
  for (int j = 0; j < 8; ++j) a[j] = (float)ysh[j];
#pragma unroll
  for (int k = 0; k < 4; ++k) {
    int sl = slot_of[t * 4 + k];
    float w = weight_sel[t * 4 + k];
    f16x8 v = *(const f16x8*)(ybuf + (size_t)sl * H_DIM + s8);
#pragma unroll
    for (int j = 0; j < 8; ++j) a[j] += w * (float)v[j];
  }
  float4 o0 = { a[0], a[1], a[2], a[3] };
  float4 o1 = { a[4], a[5], a[6], a[7] };
  *(float4*)(out + (size_t)t * H_DIM + s8) = o0;
  *(float4*)(out + (size_t)t * H_DIM + s8 + 4) = o1;
}

// ------------------------------------------------------------- launcher ---
extern "C" void kernel_launch(void* const* d_in, const int* in_sizes, int n_in,
                              void* d_out, int out_size, void* d_ws, size_t ws_size,
                              hipStream_t stream) {
  const float* x        = (const float*)d_in[0];
  const float* router_w = (const float*)d_in[1];
  const float* gate_w   = (const float*)d_in[2];
  const float* up_w     = (const float*)d_in[3];
  const float* down_w   = (const float*)d_in[4];
  const float* sgw      = (const float*)d_in[5];
  const float* suw      = (const float*)d_in[6];
  const float* sdw      = (const float*)d_in[7];
  float* out = (float*)d_out;

  char* w = (char*)d_ws;
  f16*   xb         = (f16*)w;   w += (size_t)T_TOK * H_DIM * 2;
  int*   expert_sel = (int*)w;   w += (size_t)TKTOT * 4;
  float* weight_sel = (float*)w; w += (size_t)TKTOT * 4;
  int*   slot_of    = (int*)w;   w += (size_t)TKTOT * 4;
  int*   counts     = (int*)w;   w += 256;
  int*   cursor     = (int*)w;   w += 256;
  int*   tile_exp   = (int*)w;   w += MAX_TILES * 4;
  int*   tile_row0  = (int*)w;   w += MAX_TILES * 4;
  int*   ntiles     = (int*)w;   w += 256;
  int*   row_token  = (int*)w;   w += (size_t)ROWS_MAX * 4;
  f16*   hbuf       = (f16*)w;   w += (size_t)ROWS_MAX * I_DIM * 2;
  f16*   ybuf       = (f16*)w;   w += (size_t)ROWS_MAX * H_DIM * 2;
  if ((size_t)(w - (char*)d_ws) > ws_size) return;  // ws too small: fail loud

  prep_kernel<<<(T_TOK * H_DIM / 4) / 256, 256, 0, stream>>>(x, xb, row_token, counts);
  router_kernel<<<T_TOK / 4, 256, 0, stream>>>(x, router_w, expert_sel, weight_sel, counts);
  scan_kernel<<<1, 64, 0, stream>>>(counts, cursor, tile_exp, tile_row0, ntiles);
  scatter_kernel<<<TKTOT / 256, 256, 0, stream>>>(expert_sel, cursor, row_token, slot_of);
  gemm1_kernel<<<dim3(MAX_TILES, I_DIM / 64), 256, 0, stream>>>(
      xb, gate_w, up_w, sgw, suw, row_token, tile_exp, tile_row0, ntiles, hbuf);
  gemm2_kernel<<<dim3(MAX_TILES, H_DIM / 128), 256, 0, stream>>>(
      hbuf, down_w, sdw, tile_exp, tile_row0, ntiles, ybuf);
  gather_kernel<<<(T_TOK * (H_DIM / 8)) / 256, 256, 0, stream>>>(
      ybuf, slot_of, weight_sel, out);
}

// Round 14
// 676.091 us; speedup vs baseline: 1.3910x; 1.3910x over previous
//
#include <hip/hip_runtime.h>
#include <hip/hip_bf16.h>

// Problem constants (reference: T,H,I,E,K = 4096,1024,2048,32,4)
#define T_TOK 4096
#define H_DIM 1024
#define I_DIM 2048
#define N_EXP 32
#define TOPK  4
#define TKTOT (T_TOK * TOPK)      // 16384 expert-row slots
#define ROWS_MAX 24576            // 4096 shared rows + <=20480 padded expert rows
#define MAX_TILES 192             // 32 shared tiles + <=159 expert tiles
#define BM 128
#define BK 64
#define LDB 72                    // BK + 8 f16 pad -> 144 B rows

typedef _Float16 f16;
typedef __attribute__((ext_vector_type(2))) f16  f16x2;
typedef __attribute__((ext_vector_type(4))) f16  f16x4;
typedef __attribute__((ext_vector_type(8))) f16  f16x8;
typedef __attribute__((ext_vector_type(4))) float f32x4;

// async global->LDS, 16B per lane; LDS dest is wave-uniform base + lane*16
__device__ __forceinline__ void glds16(const f16* g, f16* l) {
  __builtin_amdgcn_global_load_lds(
      (const __attribute__((address_space(1))) void*)g,
      (__attribute__((address_space(3))) void*)l, 16, 0, 0);
}
__device__ __forceinline__ void sfence() { __builtin_amdgcn_sched_barrier(0); }
// pre-MFMA barrier, counted vmcnt: retire current tile's A-glds while the
// 2-deep B prefetch (8+8) and next A (2) stay in flight.
__device__ __forceinline__ void bar_vm18() {
  sfence();
  asm volatile("s_waitcnt vmcnt(18) lgkmcnt(0)" ::: "memory");
  sfence();
  __builtin_amdgcn_s_barrier();
  sfence();
}
__device__ __forceinline__ void bar_vm10() {
  sfence();
  asm volatile("s_waitcnt vmcnt(10) lgkmcnt(0)" ::: "memory");
  sfence();
  __builtin_amdgcn_s_barrier();
  sfence();
}
__device__ __forceinline__ void bar_vm0() {
  sfence();
  asm volatile("s_waitcnt vmcnt(0) lgkmcnt(0)" ::: "memory");
  sfence();
  __builtin_amdgcn_s_barrier();
  sfence();
}
// post-MFMA barrier: A-glds of step ks+1 may only issue after all waves
// finished reading A(ks-1)'s buffer (same parity).
__device__ __forceinline__ void bar_post() {
  sfence();
  __builtin_amdgcn_s_barrier();
  sfence();
}

// ---------------------------------------------------------------- prep ----
__global__ void prep_kernel(const float* __restrict__ x, f16* __restrict__ xb,
                            int* __restrict__ row_token,
                            int* __restrict__ counts) {
  int gid = blockIdx.x * blockDim.x + threadIdx.x;   // 0 .. T*H/4-1
  float4 v = *(const float4*)(x + (size_t)gid * 4);
  f16x4 hv = { (f16)v.x, (f16)v.y, (f16)v.z, (f16)v.w };
  *(f16x4*)(xb + (size_t)gid * 4) = hv;
  if (gid < ROWS_MAX) row_token[gid] = (gid < T_TOK) ? gid : 0;
  if (gid < N_EXP) counts[gid] = 0;
}

// -------------------------------------------------------------- router ----
__global__ void router_kernel(const float* __restrict__ x,
                              const float* __restrict__ rw,
                              int* __restrict__ expert_sel,
                              float* __restrict__ weight_sel,
                              int* __restrict__ counts) {
  int wid = threadIdx.x >> 6, lane = threadIdx.x & 63;
  int t = blockIdx.x * 4 + wid;
  float xr[16];
#pragma unroll
  for (int j = 0; j < 16; ++j) xr[j] = x[(size_t)t * H_DIM + lane + j * 64];
  float l[32];
#pragma unroll
  for (int e = 0; e < 32; ++e) {
    float p = 0.f;
#pragma unroll
    for (int j = 0; j < 16; ++j) p += xr[j] * rw[(size_t)e * H_DIM + lane + j * 64];
#pragma unroll
    for (int off = 32; off; off >>= 1) p += __shfl_xor(p, off, 64);
    l[e] = p;
  }
  if (lane == 0) {
    unsigned used = 0;
    int sel[4]; float lv[4];
#pragma unroll
    for (int k = 0; k < 4; ++k) {
      float bv = -3.4e38f; int bi = 0;
#pragma unroll
      for (int e = 0; e < 32; ++e) {
        bool better = (((used >> e) & 1u) == 0u) && (l[e] > bv);
        bv = better ? l[e] : bv;
        bi = better ? e : bi;
      }
      used |= 1u << bi; sel[k] = bi; lv[k] = bv;
    }
    float m = lv[0];
    float p0 = __expf(lv[0] - m), p1 = __expf(lv[1] - m);
    float p2 = __expf(lv[2] - m), p3 = __expf(lv[3] - m);
    float s = p0 + p1 + p2 + p3;
    float wv[4] = { p0 / s, p1 / s, p2 / s, p3 / s };
#pragma unroll
    for (int k = 0; k < 4; ++k) {
      expert_sel[t * 4 + k] = sel[k];
      weight_sel[t * 4 + k] = wv[k];
      atomicAdd(&counts[sel[k]], 1);
    }
  }
}

// ---------------------------------------------------------------- scan ----
// wave-parallel: lane e handles expert e; prefix-sums via shfl_up.
__global__ void scan_kernel(const int* __restrict__ counts, int* __restrict__ cursor,
                            int* __restrict__ tile_expert, int* __restrict__ tile_row0,
                            int* __restrict__ ntiles) {
  int lane = threadIdx.x;                      // 64 threads, one wave
  if (lane < T_TOK / BM) { tile_expert[lane] = N_EXP; tile_row0[lane] = lane * BM; }
  int nte = 0, rows = 0;
  if (lane < N_EXP) {
    int c = counts[lane];
    nte = (c + BM - 1) / BM;
    rows = nte * BM;
  }
  int pnte = nte, prows = rows;
#pragma unroll
  for (int off = 1; off < 64; off <<= 1) {
    int t1 = __shfl_up(pnte, off, 64);
    int t2 = __shfl_up(prows, off, 64);
    if (lane >= off) { pnte += t1; prows += t2; }
  }
  int excl_nte = pnte - nte, excl_rows = prows - rows;
  if (lane < N_EXP) {
    int pos = T_TOK + excl_rows;
    cursor[lane] = pos;
    int tb = T_TOK / BM + excl_nte;
    for (int i = 0; i < nte; ++i) {
      tile_expert[tb + i] = lane;
      tile_row0[tb + i] = pos + i * BM;
    }
    if (lane == N_EXP - 1) ntiles[0] = tb + nte;
  }
}

// ------------------------------------------------------------- scatter ----
__global__ void scatter_kernel(const int* __restrict__ expert_sel,
                               int* __restrict__ cursor,
                               int* __restrict__ row_token,
                               int* __restrict__ slot_of) {
  int i = blockIdx.x * blockDim.x + threadIdx.x;
  if (i >= TKTOT) return;
  int e = expert_sel[i];
  int pos = atomicAdd(&cursor[e], 1);
  row_token[pos] = i >> 2;
  slot_of[i] = pos;
}

// ---------------- B staging: 2 cols x 8 k fp32 per thread (8 VMEM loads) --
struct Bf2 { float2 g[8]; };
__device__ __forceinline__ Bf2 fetch_b2(const float* __restrict__ src, size_t ldn) {
  Bf2 r;
#pragma unroll
  for (int j = 0; j < 8; ++j) r.g[j] = *(const float2*)(src + (size_t)j * ldn);
  return r;
}
__device__ __forceinline__ void write_b2(const Bf2& b, f16* __restrict__ Bs,
                                         int nq, int kr) {
  const float* ga = (const float*)b.g;        // ga[j*2 + comp]
  int ks = (8 * kr) ^ ((nq & 7) << 3);        // swizzled 16B slot (f16 units)
#pragma unroll
  for (int i = 0; i < 2; ++i) {
    union { f16x2 p[4]; f16x8 v; } u;
#pragma unroll
    for (int j = 0; j < 4; ++j)
      u.p[j] = __builtin_bit_cast(
          f16x2, __builtin_amdgcn_cvt_pkrtz(ga[(2 * j) * 2 + i],
                                            ga[(2 * j + 1) * 2 + i]));
    *(f16x8*)(Bs + (2 * nq + i) * LDB + ks) = u.v;
  }
}
// read-side mirror: write row = 2*nq+i -> key (row>>1)&7
__device__ __forceinline__ int rswz1(int row, int kf16) {
  return kf16 ^ (((row >> 1) & 7) << 3);
}

// ---------------------------------------------------------------- GEMM1 ---
// 512 threads / 8 waves. Waves 0-3 compute+stage GATE, waves 4-7 UP (matrix
// split -> acc 32 AGPR, B 2-deep prefetch only 32 VGPR). A via glds dbuf.
// Counted vmcnt(18) keeps B(ks+1),A(ks+1),B(ks+2) in flight across barrier.
__global__ __launch_bounds__(512, 2) void gemm1_kernel(
    const f16* __restrict__ xb,
    const float* __restrict__ gate_w, const float* __restrict__ up_w,
    const float* __restrict__ sgw, const float* __restrict__ suw,
    const int* __restrict__ row_token,
    const int* __restrict__ tile_expert, const int* __restrict__ tile_row0,
    const int* __restrict__ ntiles, f16* __restrict__ hbuf) {
  // XCD-aware swizzle: grid 192*32 = 6144 = 8*768 consecutive per XCD
  int d = blockIdx.y * gridDim.x + blockIdx.x;
  int l = (d & 7) * 768 + (d >> 3);
  int bx = l % MAX_TILES;
  int n0 = (l / MAX_TILES) * 64;
  if (bx >= ntiles[0]) return;
  int e = tile_expert[bx];
  int row0 = tile_row0[bx];
  const float* wg = (e < N_EXP) ? gate_w + (size_t)e * H_DIM * I_DIM : sgw;
  const float* wu = (e < N_EXP) ? up_w   + (size_t)e * H_DIM * I_DIM : suw;

  // LDS (f16): A0[8192] A1[8192] B[2 x (gate 4608 + up 4608)] = 34816 = 69.6KB
  __shared__ __align__(16) f16 smem[2 * BM * BK + 2 * 2 * 64 * LDB];
  f16* A0 = smem;
  f16* A1 = smem + BM * BK;
  f16* Bbase = smem + 2 * BM * BK;   // buf*9216 + mat*4608
  f16* Ctg = Bbase;                  // epilogue reuse: 9216 each
  f16* Ctu = Bbase + 9216;

  int tid = threadIdx.x;
  int lane = tid & 63, wid = tid >> 6;
  int mat = wid >> 2;                // 0 = gate, 1 = up
  int w4 = wid & 3;
  int wm = w4 >> 1, wn = w4 & 1;
  int lr = lane & 15, lk = (lane >> 4) * 8;

  // B staging: each half-block stages its matrix: 2 cols x 8 k per thread
  int t8 = tid & 255;
  int nq = t8 & 31, kr = t8 >> 5;    // 32 col-pairs, 8 k-groups
  const float* wsrc = (mat ? wu : wg) + (size_t)(8 * kr) * I_DIM + n0 + 2 * nq;

  // A glds: 2 rounds of 512 lanes; source col pre-swizzled on local row
  const f16* abase0;
  const f16* abase1;
  {
    int idx = tid;
    int arow = idx >> 3, sl = idx & 7;
    abase0 = xb + (size_t)row_token[row0 + arow] * H_DIM + ((sl ^ (arow & 7)) << 3);
    idx = tid + 512;
    arow = idx >> 3; sl = idx & 7;
    abase1 = xb + (size_t)row_token[row0 + arow] * H_DIM + ((sl ^ (arow & 7)) << 3);
  }

  f32x4 acc[4][2];
#pragma unroll
  for (int m = 0; m < 4; ++m)
#pragma unroll
    for (int n = 0; n < 2; ++n) acc[m][n] = (f32x4)0.f;

  const int NK = H_DIM / BK;         // 16

  // prologue: B(0) [8], A(0) [2], B(1) [8]
  Bf2 pb0 = fetch_b2(wsrc, I_DIM);
  sfence();
  glds16(abase0, A0 + tid * 8);
  glds16(abase1, A0 + (tid + 512) * 8);
  sfence();
  Bf2 pb1 = fetch_b2(wsrc + (size_t)BK * I_DIM, I_DIM);
  sfence();

#define G1_MFMA(ASRC, BSRC)                                                  \
  {                                                                          \
    const f16* As_ = (ASRC);                                                 \
    const f16* Bs_ = (BSRC);                                                 \
    __builtin_amdgcn_s_setprio(1);                                           \
    _Pragma("unroll")                                                        \
    for (int kk = 0; kk < BK; kk += 32) {                                    \
      f16x8 a[4], b[2];                                                      \
      _Pragma("unroll")                                                      \
      for (int m = 0; m < 4; ++m) {                                          \
        int ar = wm * 64 + m * 16 + lr;                                      \
        int ko = (kk + lk) ^ ((ar & 7) << 3);                                \
        a[m] = *(const f16x8*)(As_ + ar * BK + ko);                          \
      }                                                                      \
      _Pragma("unroll")                                                      \
      for (int n = 0; n < 2; ++n) {                                          \
        int rowb = wn * 32 + n * 16 + lr;                                    \
        b[n] = *(const f16x8*)(Bs_ + rowb * LDB + rswz1(rowb, kk + lk));     \
      }                                                                      \
      _Pragma("unroll")                                                      \
      for (int m = 0; m < 4; ++m)                                            \
        _Pragma("unroll")                                                    \
        for (int n = 0; n < 2; ++n)                                          \
          acc[m][n] = __builtin_amdgcn_mfma_f32_16x16x32_f16(a[m], b[n], acc[m][n], 0, 0, 0); \
    }                                                                        \
    __builtin_amdgcn_s_setprio(0);                                           \
  }

  for (int ks = 0; ks < NK - 2; ks += 2) {
    { // even step ks: B in pb0 (fetched at ks-2), A in A0
      write_b2(pb0, Bbase + 0 * 9216 + mat * 4608, nq, kr);
      sfence();
      glds16(abase0 + (ks + 1) * BK, A1 + tid * 8);
      glds16(abase1 + (ks + 1) * BK, A1 + (tid + 512) * 8);
      sfence();
      pb0 = fetch_b2(wsrc + (size_t)(ks + 2) * BK * I_DIM, I_DIM);
      sfence();
      bar_vm18();
      G1_MFMA(A0, Bbase + 0 * 9216 + mat * 4608);
      bar_post();
    }
    { // odd step ks+1: B in pb1, A in A1
      write_b2(pb1, Bbase + 1 * 9216 + mat * 4608, nq, kr);
      sfence();
      glds16(abase0 + (ks + 2) * BK, A0 + tid * 8);
      glds16(abase1 + (ks + 2) * BK, A0 + (tid + 512) * 8);
      sfence();
      pb1 = fetch_b2(wsrc + (size_t)(ks + 3) * BK * I_DIM, I_DIM);
      sfence();
      bar_vm18();
      G1_MFMA(A1, Bbase + 1 * 9216 + mat * 4608);
      bar_post();
    }
  }
  { // peeled step NK-2 (even): issue only A(NK-1)
    write_b2(pb0, Bbase + 0 * 9216 + mat * 4608, nq, kr);
    sfence();
    glds16(abase0 + (NK - 1) * BK, A1 + tid * 8);
    glds16(abase1 + (NK - 1) * BK, A1 + (tid + 512) * 8);
    sfence();
    bar_vm10();    // need A(NK-2); newer: B(NK-1)=8 + A(NK-1)=2
    G1_MFMA(A0, Bbase + 0 * 9216 + mat * 4608);
    bar_post();
  }
  { // peeled step NK-1 (odd)
    write_b2(pb1, Bbase + 1 * 9216 + mat * 4608, nq, kr);
    bar_vm0();
    G1_MFMA(A1, Bbase + 1 * 9216 + mat * 4608);
  }
#undef G1_MFMA

  // epilogue: gate waves write silu(g), up waves write u; combine; store.
  __syncthreads();
  {
    f16* ct = mat ? Ctu : Ctg;
#pragma unroll
    for (int m = 0; m < 4; ++m)
#pragma unroll
      for (int n = 0; n < 2; ++n)
#pragma unroll
        for (int j = 0; j < 4; ++j) {
          float v = acc[m][n][j];
          if (mat == 0) v = v / (1.f + __expf(-v));   // silu(gate)
          ct[(wm * 64 + m * 16 + (lane >> 4) * 4 + j) * LDB +
             wn * 32 + n * 16 + lr] = (f16)v;
        }
  }
  __syncthreads();
#pragma unroll
  for (int it = 0; it < 2; ++it) {
    int idx = tid + it * 512;
    int r = idx >> 3, g8 = (idx & 7) * 8;
    f16x8 g = *(const f16x8*)(Ctg + r * LDB + g8);
    f16x8 u = *(const f16x8*)(Ctu + r * LDB + g8);
    f16x8 h;
#pragma unroll
    for (int j = 0; j < 8; ++j) h[j] = g[j] * u[j];
    *(f16x8*)(hbuf + (size_t)(row0 + r) * I_DIM + n0 + g8) = h;
  }
}

// ---------------------------------------------------------------- GEMM2 ---
// 512 threads / 8 waves (2x4 grid), 128x128 tile of down. Same pipeline:
// A (hbuf) glds dbuf, B 2-deep reg prefetch, vmcnt(18). Output ybuf f16.
__global__ __launch_bounds__(512, 2) void gemm2_kernel(
    const f16* __restrict__ hbuf,
    const float* __restrict__ down_w, const float* __restrict__ sdw,
    const int* __restrict__ tile_expert, const int* __restrict__ tile_row0,
    const int* __restrict__ ntiles, f16* __restrict__ ybuf) {
  // grid 192*8 = 1536 = 8*192 consecutive per XCD
  int d = blockIdx.y * gridDim.x + blockIdx.x;
  int l = (d & 7) * 192 + (d >> 3);
  int bx = l % MAX_TILES;
  int n0 = (l / MAX_TILES) * 128;
  if (bx >= ntiles[0]) return;
  int e = tile_expert[bx];
  int row0 = tile_row0[bx];
  const float* wd = (e < N_EXP) ? down_w + (size_t)e * I_DIM * H_DIM : sdw;

  // LDS (f16): A0[8192] A1[8192] B dbuf [2 x 128*72 = 18432] = 34816
  __shared__ __align__(16) f16 smem[2 * BM * BK + 2 * 128 * LDB];
  f16* A0 = smem;
  f16* A1 = smem + BM * BK;
  f16* Bbase = smem + 2 * BM * BK;   // + buf*9216
  f16 (*Ct)[136] = (f16(*)[136])Bbase;  // 17408 <= 18432

  int tid = threadIdx.x;
  int lane = tid & 63, wid = tid >> 6;
  int wm = wid >> 2, wn = wid & 3;   // 2 x 4 wave grid; per wave 64 x 32
  int lr = lane & 15, lk = (lane >> 4) * 8;

  int nq = tid & 63, kr = tid >> 6;  // 64 col-pairs, 8 k-groups
  const float* wsrc = wd + (size_t)(8 * kr) * H_DIM + n0 + 2 * nq;

  const f16* abase0;
  const f16* abase1;
  {
    int idx = tid;
    int arow = idx >> 3, sl = idx & 7;
    abase0 = hbuf + (size_t)(row0 + arow) * I_DIM + ((sl ^ (arow & 7)) << 3);
    idx = tid + 512;
    arow = idx >> 3; sl = idx & 7;
    abase1 = hbuf + (size_t)(row0 + arow) * I_DIM + ((sl ^ (arow & 7)) << 3);
  }

  f32x4 acc[4][2];
#pragma unroll
  for (int m = 0; m < 4; ++m)
#pragma unroll
    for (int n = 0; n < 2; ++n) acc[m][n] = (f32x4)0.f;

  const int NK = I_DIM / BK;         // 32

  Bf2 pb0 = fetch_b2(wsrc, H_DIM);
  sfence();
  glds16(abase0, A0 + tid * 8);
  glds16(abase1, A0 + (tid + 512) * 8);
  sfence();
  Bf2 pb1 = fetch_b2(wsrc + (size_t)BK * H_DIM, H_DIM);
  sfence();

#define G2_MFMA(ASRC, BSRC)                                                  \
  {                                                                          \
    const f16* As_ = (ASRC);                                                 \
    const f16* Bs_ = (BSRC);                                                 \
    __builtin_amdgcn_s_setprio(1);                                           \
    _Pragma("unroll")                                                        \
    for (int kk = 0; kk < BK; kk += 32) {                                    \
      f16x8 a[4], b[2];                                                      \
      _Pragma("unroll")                                                      \
      for (int m = 0; m < 4; ++m) {                                          \
        int ar = wm * 64 + m * 16 + lr;                                      \
        int ko = (kk + lk) ^ ((ar & 7) << 3);                                \
        a[m] = *(const f16x8*)(As_ + ar * BK + ko);                          \
      }                                                                      \
      _Pragma("unroll")                                                      \
      for (int n = 0; n < 2; ++n) {                                          \
        int rowb = wn * 32 + n * 16 + lr;                                    \
        b[n] = *(const f16x8*)(Bs_ + rowb * LDB + rswz1(rowb, kk + lk));     \
      }                                                                      \
      _Pragma("unroll")                                                      \
      for (int m = 0; m < 4; ++m)                                            \
        _Pragma("unroll")                                                    \
        for (int n = 0; n < 2; ++n)                                          \
          acc[m][n] = __builtin_amdgcn_mfma_f32_16x16x32_f16(a[m], b[n], acc[m][n], 0, 0, 0); \
    }                                                                        \
    __builtin_amdgcn_s_setprio(0);                                           \
  }

  for (int ks = 0; ks < NK - 2; ks += 2) {
    { // even
      write_b2(pb0, Bbase + 0 * 9216, nq, kr);
      sfence();
      glds16(abase0 + (ks + 1) * BK, A1 + tid * 8);
      glds16(abase1 + (ks + 1) * BK, A1 + (tid + 512) * 8);
      sfence();
      pb0 = fetch_b2(wsrc + (size_t)(ks + 2) * BK * H_DIM, H_DIM);
      sfence();
      bar_vm18();
      G2_MFMA(A0, Bbase + 0 * 9216);
      bar_post();
    }
    { // odd
      write_b2(pb1, Bbase + 1 * 9216, nq, kr);
      sfence();
      glds16(abase0 + (ks + 2) * BK, A0 + tid * 8);
      glds16(abase1 + (ks + 2) * BK, A0 + (tid + 512) * 8);
      sfence();
      pb1 = fetch_b2(wsrc + (size_t)(ks + 3) * BK * H_DIM, H_DIM);
      sfence();
      bar_vm18();
      G2_MFMA(A1, Bbase + 1 * 9216);
      bar_post();
    }
  }
  { // peeled NK-2
    write_b2(pb0, Bbase + 0 * 9216, nq, kr);
    sfence();
    glds16(abase0 + (NK - 1) * BK, A1 + tid * 8);
    glds16(abase1 + (NK - 1) * BK, A1 + (tid + 512) * 8);
    sfence();
    bar_vm10();
    G2_MFMA(A0, Bbase + 0 * 9216);
    bar_post();
  }
  { // peeled NK-1
    write_b2(pb1, Bbase + 1 * 9216, nq, kr);
    bar_vm0();
    G2_MFMA(A1, Bbase + 1 * 9216);
  }
#undef G2_MFMA

  __syncthreads();
#pragma unroll
  for (int m = 0; m < 4; ++m)
#pragma unroll
    for (int n = 0; n < 2; ++n)
#pragma unroll
      for (int j = 0; j < 4; ++j)
        Ct[wm * 64 + m * 16 + (lane >> 4) * 4 + j][wn * 32 + n * 16 + lr] =
            (f16)acc[m][n][j];
  __syncthreads();
#pragma unroll
  for (int it = 0; it < 4; ++it) {
    int idx = tid + it * 512;
    int r = idx >> 4, g8 = (idx & 15) * 8;
    *(f16x8*)(ybuf + (size_t)(row0 + r) * H_DIM + n0 + g8) = *(const f16x8*)&Ct[r][g8];
  }
}

// --------------------------------------------------------------- gather ---
// out[t] = ybuf[t] (shared) + sum_k w[t,k] * ybuf[slot_of[t,k]]
__global__ void gather_kernel(const f16* __restrict__ ybuf,
                              const int* __restrict__ slot_of,
                              const float* __restrict__ weight_sel,
                              float* __restrict__ out) {
  int gid = blockIdx.x * blockDim.x + threadIdx.x;   // T*128
  int t = gid >> 7, s8 = (gid & 127) * 8;
  f16x8 ysh = *(const f16x8*)(ybuf + (size_t)t * H_DIM + s8);
  float a[8];
#pragma unroll
  for (int j = 0; j < 8; ++j) a[j] = (float)ysh[j];
#pragma unroll
  for (int k = 0; k < 4; ++k) {
    int sl = slot_of[t * 4 + k];
    float w = weight_sel[t * 4 + k];
    f16x8 v = *(const f16x8*)(ybuf + (size_t)sl * H_DIM + s8);
#pragma unroll
    for (int j = 0; j < 8; ++j) a[j] += w * (float)v[j];
  }
  float4 o0 = { a[0], a[1], a[2], a[3] };
  float4 o1 = { a[4], a[5], a[6], a[7] };
  *(float4*)(out + (size_t)t * H_DIM + s8) = o0;
  *(float4*)(out + (size_t)t * H_DIM + s8 + 4) = o1;
}

// ------------------------------------------------------------- launcher ---
extern "C" void kernel_launch(void* const* d_in, const int* in_sizes, int n_in,
                              void* d_out, int out_size, void* d_ws, size_t ws_size,
                              hipStream_t stream) {
  const float* x        = (const float*)d_in[0];
  const float* router_w = (const float*)d_in[1];
  const float* gate_w   = (const float*)d_in[2];
  const float* up_w     = (const float*)d_in[3];
  const float* down_w   = (const float*)d_in[4];
  const float* sgw      = (const float*)d_in[5];
  const float* suw      = (const float*)d_in[6];
  const float* sdw      = (const float*)d_in[7];
  float* out = (float*)d_out;

  char* w = (char*)d_ws;
  f16*   xb         = (f16*)w;   w += (size_t)T_TOK * H_DIM * 2;
  int*   expert_sel = (int*)w;   w += (size_t)TKTOT * 4;
  float* weight_sel = (float*)w; w += (size_t)TKTOT * 4;
  int*   slot_of    = (int*)w;   w += (size_t)TKTOT * 4;
  int*   counts     = (int*)w;   w += 256;
  int*   cursor     = (int*)w;   w += 256;
  int*   tile_exp   = (int*)w;   w += MAX_TILES * 4;
  int*   tile_row0  = (int*)w;   w += MAX_TILES * 4;
  int*   ntiles     = (int*)w;   w += 256;
  int*   row_token  = (int*)w;   w += (size_t)ROWS_MAX * 4;
  f16*   hbuf       = (f16*)w;   w += (size_t)ROWS_MAX * I_DIM * 2;
  f16*   ybuf       = (f16*)w;   w += (size_t)ROWS_MAX * H_DIM * 2;
  if ((size_t)(w - (char*)d_ws) > ws_size) return;  // ws too small: fail loud

  prep_kernel<<<(T_TOK * H_DIM / 4) / 256, 256, 0, stream>>>(x, xb, row_token, counts);
  router_kernel<<<T_TOK / 4, 256, 0, stream>>>(x, router_w, expert_sel, weight_sel, counts);
  scan_kernel<<<1, 64, 0, stream>>>(counts, cursor, tile_exp, tile_row0, ntiles);
  scatter_kernel<<<TKTOT / 256, 256, 0, stream>>>(expert_sel, cursor, row_token, slot_of);
  gemm1_kernel<<<dim3(MAX_TILES, I_DIM / 64), 512, 0, stream>>>(
      xb, gate_w, up_w, sgw, suw, row_token, tile_exp, tile_row0, ntiles, hbuf);
  gemm2_kernel<<<dim3(MAX_TILES, H_DIM / 128), 512, 0, stream>>>(
      hbuf, down_w, sdw, tile_exp, tile_row0, ntiles, ybuf);
  gather_kernel<<<(T_TOK * (H_DIM / 8)) / 256, 256, 0, stream>>>(
      ybuf, slot_of, weight_sel, out);
}